// Round 7
// baseline (339.984 us; speedup 1.0000x reference)
//
#include <hip/hip_runtime.h>

#define NEG_SLOPE 0.2f
#define BN_EPS 1e-5f
#define LN_EPS 1e-5f

typedef __bf16 bf16_t;
typedef bf16_t bf16x8 __attribute__((ext_vector_type(8)));
typedef float floatx4 __attribute__((ext_vector_type(4)));
typedef float floatx2 __attribute__((ext_vector_type(2)));

__device__ __forceinline__ unsigned short f2bf(float f) {
  unsigned u = __float_as_uint(f);
  u += 0x7FFFu + ((u >> 16) & 1u);
  return (unsigned short)(u >> 16);
}
__device__ __forceinline__ float bf_lo(unsigned u) { return __uint_as_float(u << 16); }
__device__ __forceinline__ float bf_hi(unsigned u) { return __uint_as_float(u & 0xFFFF0000u); }

// ---------------- fused: conversions + BN fold + edge degree count (8 edges/thread) ----------------
__global__ void cvt_all(const float* __restrict__ x,
                        const float* __restrict__ wl1, const float* __restrict__ wr1,
                        const float* __restrict__ wl2, const float* __restrict__ wr2,
                        const float* __restrict__ wsk,
                        const float* __restrict__ bias1,
                        const float* __restrict__ bn_w, const float* __restrict__ bn_b,
                        const float* __restrict__ bn_rm, const float* __restrict__ bn_rv,
                        const int* __restrict__ ei, int E, int ET,
                        unsigned short* __restrict__ xbf,
                        unsigned short* __restrict__ wcat1,  // 272 x 128
                        unsigned short* __restrict__ wcat2,  // 256 x 128
                        int* __restrict__ deg, unsigned short* __restrict__ rpos,
                        float* __restrict__ bnS, float* __restrict__ bnT,
                        int n4x) {
  const int W4 = 128 * 128 / 4;  // 4096
  const int S4 = 16 * 128 / 4;   // 512
  int i = blockIdx.x * blockDim.x + threadIdx.x;
  const float* src;
  unsigned short* dst;
  int j;
  if (i < n4x) { src = x; dst = xbf; j = i; }
  else {
    j = i - n4x;
    if (j < W4)               { src = wl1; dst = wcat1; }
    else if (j < 2 * W4)      { src = wr1; dst = wcat1 + 128 * 128; j -= W4; }
    else if (j < 3 * W4)      { src = wl2; dst = wcat2; j -= 2 * W4; }
    else if (j < 4 * W4)      { src = wr2; dst = wcat2 + 128 * 128; j -= 3 * W4; }
    else if (j < 4 * W4 + S4) { src = wsk; dst = wcat1 + 256 * 128; j -= 4 * W4; }
    else {
      j -= 4 * W4 + S4;
      if (j < 32) {
        for (int t = j * 4; t < j * 4 + 4; ++t) {
          float S = bn_w[t] * rsqrtf(bn_rv[t] + BN_EPS);
          bnS[t] = S;
          bnT[t] = (bias1[t] - bn_rm[t]) * S + bn_b[t];
        }
      } else {
        int t = j - 32;
        if (t < ET) {
#pragma unroll
          for (int k = 0; k < 8; ++k) {
            int e = t + k * ET;  // coalesced across threads, 8 independent atomics in flight
            if (e < E) {
              int d = ei[E + e];
              rpos[e] = (unsigned short)atomicAdd(&deg[d], 1);
            }
          }
        }
      }
      return;
    }
  }
  float4 v = ((const float4*)src)[j];
  ushort4 o;
  o.x = f2bf(v.x); o.y = f2bf(v.y); o.z = f2bf(v.z); o.w = f2bf(v.w);
  ((ushort4*)dst)[j] = o;
}

// ---------------- CSR scan (degrees rounded up to EVEN -> even segment starts) ----------------
__global__ __launch_bounds__(1024)
void scan_deg(const int* __restrict__ deg, int* __restrict__ indptr, int n) {
  __shared__ int carry;
  __shared__ int wsum[16];
  int lane = threadIdx.x & 63, wid = threadIdx.x >> 6;
  if (threadIdx.x == 0) { carry = 0; indptr[0] = 0; }
  __syncthreads();
  for (int base = 0; base < n; base += 4096) {
    int i0 = base + (int)threadIdx.x * 4;
    int4 v = make_int4(0, 0, 0, 0);
    if (i0 + 3 < n) v = *(const int4*)(deg + i0);
    else {
      if (i0 < n)     v.x = deg[i0];
      if (i0 + 1 < n) v.y = deg[i0 + 1];
      if (i0 + 2 < n) v.z = deg[i0 + 2];
      if (i0 + 3 < n) v.w = deg[i0 + 3];
    }
    v.x = (v.x + 1) & ~1; v.y = (v.y + 1) & ~1; v.z = (v.z + 1) & ~1; v.w = (v.w + 1) & ~1;
    int s1 = v.x, s2 = s1 + v.y, s3 = s2 + v.z, s4 = s3 + v.w;
    int s = s4;
#pragma unroll
    for (int d = 1; d < 64; d <<= 1) { int t = __shfl_up(s, d, 64); if (lane >= d) s += t; }
    if (lane == 63) wsum[wid] = s;
    __syncthreads();
    if (threadIdx.x < 16) {
      int ws = wsum[threadIdx.x];
#pragma unroll
      for (int d = 1; d < 16; d <<= 1) { int t = __shfl_up(ws, d, 16); if ((int)threadIdx.x >= d) ws += t; }
      wsum[threadIdx.x] = ws;
    }
    __syncthreads();
    int off = carry + (wid ? wsum[wid - 1] : 0) + (s - s4);  // exclusive prefix
    if (i0 < n)     indptr[i0 + 1] = off + s1;
    if (i0 + 1 < n) indptr[i0 + 2] = off + s2;
    if (i0 + 2 < n) indptr[i0 + 3] = off + s3;
    if (i0 + 3 < n) indptr[i0 + 4] = off + s4;
    __syncthreads();
    if (threadIdx.x == 0) carry += wsum[15];
    __syncthreads();
  }
}

// ---------------- scatter, 4 edges/thread ----------------
__global__ void scatter_edges(const int* __restrict__ ei, int E, int ST,
                              const int* __restrict__ indptr,
                              const unsigned short* __restrict__ rpos,
                              unsigned short* __restrict__ csr) {
  int t = blockIdx.x * blockDim.x + threadIdx.x;
  if (t >= ST) return;
#pragma unroll
  for (int k = 0; k < 4; ++k) {
    int e = t + k * ST;
    if (e < E) {
      int d = ei[E + e];
      csr[indptr[d] + (int)rpos[e]] = (unsigned short)ei[e];
    }
  }
}

// ---------------- bf16 MFMA GEMM:  C = A[M,128] * B[P,128]^T + bias ----------------
// one wave = 32(M) x 64(P); K=128 register-resident; B frags shared across 2 m-tiles.
template <bool MIXED>
__global__ __launch_bounds__(256)
void gemm_bf16_mfma(const unsigned short* __restrict__ A, const unsigned short* __restrict__ B,
                    const float* __restrict__ bias0, const float* __restrict__ bias1,
                    unsigned short* __restrict__ Cbf, float* __restrict__ Cf,
                    int M, int pstrips) {
  int wave = (int)((blockIdx.x * blockDim.x + threadIdx.x) >> 6);
  int lane = threadIdx.x & 63;
  int mtiles = (M + 31) >> 5;
  if (wave >= mtiles * pstrips) return;
  int mt = wave % mtiles, ps = wave / mtiles;
  int r = lane & 15, quad = lane >> 4;

  const unsigned short* Abase = A + (size_t)(mt * 32 + r) * 128 + quad * 8;
  bf16x8 a0[4], a1[4];
#pragma unroll
  for (int k = 0; k < 4; ++k) {
    a0[k] = *(const bf16x8*)(Abase + 32 * k);
    a1[k] = *(const bf16x8*)(Abase + 16 * 128 + 32 * k);  // guarded at store
  }

  int row0 = mt * 32 + quad * 4;
  const int Ptot = MIXED ? 272 : 256;
#pragma unroll
  for (int pp = 0; pp < 4; ++pp) {
    int p0 = ps * 64 + pp * 16;
    if (p0 >= Ptot) break;
    const unsigned short* Bbase = B + (size_t)(p0 + r) * 128 + quad * 8;
    bf16x8 b[4];
#pragma unroll
    for (int k = 0; k < 4; ++k) b[k] = *(const bf16x8*)(Bbase + 32 * k);
    floatx4 acc0 = {0.f, 0.f, 0.f, 0.f};
    floatx4 acc1 = {0.f, 0.f, 0.f, 0.f};
#pragma unroll
    for (int k = 0; k < 4; ++k) {
      acc0 = __builtin_amdgcn_mfma_f32_16x16x32_bf16(a0[k], b[k], acc0, 0, 0, 0);
      acc1 = __builtin_amdgcn_mfma_f32_16x16x32_bf16(a1[k], b[k], acc1, 0, 0, 0);
    }
    int col = p0 + r;
    if (MIXED && col >= 256) {
#pragma unroll
      for (int i = 0; i < 4; ++i) {
        if (row0 + i < M)      Cf[(size_t)(row0 + i) * 16 + (col - 256)] = acc0[i];
        if (row0 + 16 + i < M) Cf[(size_t)(row0 + 16 + i) * 16 + (col - 256)] = acc1[i];
      }
    } else {
      float bs = (col < 128) ? bias0[col] : bias1[col - 128];
#pragma unroll
      for (int i = 0; i < 4; ++i) {
        if (row0 + i < M)      Cbf[(size_t)(row0 + i) * 256 + col] = f2bf(acc0[i] + bs);
        if (row0 + 16 + i < M) Cbf[(size_t)(row0 + 16 + i) * 256 + col] = f2bf(acc1[i] + bs);
      }
    }
  }
}

// ---------------- GATv2 aggregation: persistent waves, scalar indices, packed-f32 math ----------------
// xlr row: [256 bf16] = 128 u32; u32 cols 0..63 = xl ch0..127, 64..127 = xr.
// 32 lanes per edge (4 ch/lane, 2x floatx2); two halves process a csr pair; 4 pairs unrolled.
// leakyrelu via v_pk_max: lr(e) = max(e, 0.2e)  (exact; VOP3P has no abs modifier).
template <int LAYER>
__global__ __launch_bounds__(256)
void gat_agg(const unsigned int* __restrict__ xlr,
             const int* __restrict__ indptr, const int* __restrict__ deg,
             const unsigned short* __restrict__ csr,
             const float* __restrict__ att,
             const float* __restrict__ p0, const float* __restrict__ p1,
             const float* __restrict__ p2, const float* __restrict__ p3,
             void* __restrict__ outp, int n, int nwaves) {
  int lane = threadIdx.x & 63;
  int gw = (int)((blockIdx.x * blockDim.x + threadIdx.x) >> 6);
  int half = lane >> 5, sl = lane & 31;
  float4 at = ((const float4*)att)[sl];
  floatx2 a01 = {at.x, at.y}, a23 = {at.z, at.w};

  for (int dst = gw; dst < n; dst += nwaves) {
    int dsts = __builtin_amdgcn_readfirstlane(dst);
    int beg = __builtin_amdgcn_readfirstlane(indptr[dsts]);
    int dg = __builtin_amdgcn_readfirstlane(deg[dsts]);
    const unsigned* cp = (const unsigned*)csr + (beg >> 1);  // beg is even
    int tot = dg + 1;                // + self-loop
    int npair = (tot + 1) >> 1;

    uint2 ur = *(const uint2*)(xlr + (size_t)dsts * 128 + 64 + sl * 2);
    floatx2 xr01 = {bf_lo(ur.x), bf_hi(ur.x)};
    floatx2 xr23 = {bf_lo(ur.y), bf_hi(ur.y)};
    float lA = 0.f, lB = 0.f;
    floatx2 cA01 = {0.f, 0.f}, cA23 = {0.f, 0.f};
    floatx2 cB01 = {0.f, 0.f}, cB23 = {0.f, 0.f};

    for (int p = 0; p < npair; p += 4) {
      uint2 u[4];
      float vm[4];
#pragma unroll
      for (int k = 0; k < 4; ++k) {
        unsigned pr = cp[p + k];          // scalar s_load; pad over-read masked below
        int e0 = 2 * (p + k), e1 = e0 + 1;
        int sA = (e0 < dg) ? (int)(pr & 0xFFFFu) : dsts;
        int sB = (e1 < dg) ? (int)(pr >> 16) : dsts;
        float mA = (e0 < tot) ? 1.f : 0.f;
        float mB = (e1 < tot) ? 1.f : 0.f;
        int s = half ? sB : sA;
        vm[k] = half ? mB : mA;
        u[k] = *(const uint2*)(xlr + ((size_t)s << 7) + sl * 2);
      }
#pragma unroll
      for (int k = 0; k < 4; ++k) {
        floatx2 x01 = {bf_lo(u[k].x), bf_hi(u[k].x)};
        floatx2 x23 = {bf_lo(u[k].y), bf_hi(u[k].y)};
        floatx2 e01 = x01 + xr01;
        floatx2 e23 = x23 + xr23;
        floatx2 t01 = __builtin_elementwise_max(e01, e01 * NEG_SLOPE);
        floatx2 t23 = __builtin_elementwise_max(e23, e23 * NEG_SLOPE);
        floatx2 s2 = t01 * a01 + t23 * a23;
        float sc = s2.x + s2.y;
        sc += __shfl_xor(sc, 1);
        sc += __shfl_xor(sc, 2);          // per-head score (4 lanes = 16 ch)
        float pw = __expf(sc) * vm[k];
        floatx2 pv = {pw, pw};
        if (k & 1) {
          lB += pw;
          cB01 = x01 * pv + cB01;
          cB23 = x23 * pv + cB23;
        } else {
          lA += pw;
          cA01 = x01 * pv + cA01;
          cA23 = x23 * pv + cA23;
        }
      }
    }
    float l = lA + lB;
    floatx2 c01 = cA01 + cB01, c23 = cA23 + cB23;
    l += __shfl_xor(l, 32);
    float c0 = c01.x + __shfl_xor(c01.x, 32);
    float c1 = c01.y + __shfl_xor(c01.y, 32);
    float c2 = c23.x + __shfl_xor(c23.x, 32);
    float c3 = c23.y + __shfl_xor(c23.y, 32);
    float inv = 1.f / l;

    if (LAYER == 1) {
      // p0=bnS p1=bnT (bias1+BN prefolded); channels 4sl..4sl+3
      float4 S = ((const float4*)p0)[sl];
      float4 T = ((const float4*)p1)[sl];
      float o0 = fmaf(c0 * inv, S.x, T.x);
      float o1 = fmaf(c1 * inv, S.y, T.y);
      float o2 = fmaf(c2 * inv, S.z, T.z);
      float o3 = fmaf(c3 * inv, S.w, T.w);
      o0 = (o0 > 0.f) ? o0 : (__expf(o0) - 1.f);
      o1 = (o1 > 0.f) ? o1 : (__expf(o1) - 1.f);
      o2 = (o2 > 0.f) ? o2 : (__expf(o2) - 1.f);
      o3 = (o3 > 0.f) ? o3 : (__expf(o3) - 1.f);
      if (half == 0) {
        uint2 o;
        o.x = ((unsigned)f2bf(o1) << 16) | f2bf(o0);
        o.y = ((unsigned)f2bf(o3) << 16) | f2bf(o2);
        ((uint2*)outp)[(size_t)dst * 32 + sl] = o;
      }
    } else {
      // p0=xres p1=bias2 p2=ln_w p3=ln_b ; head = sl>>2
      float y0 = c0 * inv, y1 = c1 * inv, y2 = c2 * inv, y3 = c3 * inv;
#pragma unroll
      for (int d = 4; d <= 16; d <<= 1) {
        y0 += __shfl_xor(y0, d); y1 += __shfl_xor(y1, d);
        y2 += __shfl_xor(y2, d); y3 += __shfl_xor(y3, d);
      }
      int chh = (sl & 3) * 4;
      float4 b2 = *(const float4*)(p1 + chh);
      float4 xs = *(const float4*)(p0 + (size_t)dst * 16 + chh);
      y0 = y0 * 0.125f + b2.x + xs.x;
      y1 = y1 * 0.125f + b2.y + xs.y;
      y2 = y2 * 0.125f + b2.z + xs.z;
      y3 = y3 * 0.125f + b2.w + xs.w;
      float t = (y0 + y1) + (y2 + y3);
      t += __shfl_xor(t, 1); t += __shfl_xor(t, 2);
      float mu = t * (1.f / 16.f);
      float d0 = y0 - mu, d1 = y1 - mu, d2 = y2 - mu, d3 = y3 - mu;
      float v = (d0 * d0 + d1 * d1) + (d2 * d2 + d3 * d3);
      v += __shfl_xor(v, 1); v += __shfl_xor(v, 2);
      float istd = rsqrtf(v * (1.f / 16.f) + LN_EPS);
      float4 lw = *(const float4*)(p2 + chh);
      float4 lb = *(const float4*)(p3 + chh);
      if (lane < 4) {
        float4 o;
        o.x = d0 * istd * lw.x + lb.x;
        o.y = d1 * istd * lw.y + lb.y;
        o.z = d2 * istd * lw.z + lb.z;
        o.w = d3 * istd * lw.w + lb.w;
        *(float4*)((float*)outp + (size_t)dst * 16 + chh) = o;
      }
    }
  }
}

extern "C" void kernel_launch(void* const* d_in, const int* in_sizes, int n_in,
                              void* d_out, int out_size, void* d_ws, size_t ws_size,
                              hipStream_t stream) {
  const float* x     = (const float*)d_in[0];
  const int*   ei    = (const int*)d_in[1];
  const float* Wl1   = (const float*)d_in[2];
  const float* bl1   = (const float*)d_in[3];
  const float* Wr1   = (const float*)d_in[4];
  const float* br1   = (const float*)d_in[5];
  const float* att1  = (const float*)d_in[6];
  const float* bias1 = (const float*)d_in[7];
  const float* bn_w  = (const float*)d_in[8];
  const float* bn_b  = (const float*)d_in[9];
  const float* bn_rm = (const float*)d_in[10];
  const float* bn_rv = (const float*)d_in[11];
  const float* Wl2   = (const float*)d_in[12];
  const float* bl2   = (const float*)d_in[13];
  const float* Wr2   = (const float*)d_in[14];
  const float* br2   = (const float*)d_in[15];
  const float* att2  = (const float*)d_in[16];
  const float* bias2 = (const float*)d_in[17];
  const float* Wskip = (const float*)d_in[18];
  const float* ln_w  = (const float*)d_in[19];
  const float* ln_b  = (const float*)d_in[20];

  const int N = in_sizes[0] / 128;  // 50000
  const int E = in_sizes[1] / 2;    // 800000

  char* w = (char*)d_ws;
  size_t off = 0;
  auto alloc = [&](size_t bytes) -> void* {
    void* p = (void*)(w + off);
    off += (bytes + 255) & ~(size_t)255;
    return p;
  };
  unsigned short* xbf    = (unsigned short*)alloc((size_t)N * 128 * 2);
  unsigned short* wcat1  = (unsigned short*)alloc(272 * 128 * 2);  // [Wl1|Wr1|Wskip]
  unsigned short* wcat2  = (unsigned short*)alloc(256 * 128 * 2);  // [Wl2|Wr2]
  unsigned int*   xlr    = (unsigned int*)alloc((size_t)N * 128 * 4);  // bf16 [N,256]
  float*          xres   = (float*)alloc((size_t)N * 16 * 4);
  unsigned short* hbf    = (unsigned short*)alloc((size_t)N * 128 * 2);
  float*          bnS    = (float*)alloc(128 * 4);
  float*          bnT    = (float*)alloc(128 * 4);
  int*            deg    = (int*)alloc((size_t)N * 4);
  int*            indptr = (int*)alloc((size_t)(N + 1) * 4);
  unsigned short* rpos   = (unsigned short*)alloc((size_t)E * 2);
  unsigned short* csr    = (unsigned short*)alloc((size_t)(E + N) * 2 + 256);  // even-padded + slack

  // --- deg = 0, then fused conversions + BN fold + degree count ---
  hipMemsetAsync(deg, 0, (size_t)N * 4, stream);
  {
    int n4x = (N * 128) / 4;
    int ET = (E + 7) / 8;
    int tot = n4x + 4 * (128 * 128 / 4) + (16 * 128 / 4) + 32 + ET;
    cvt_all<<<(tot + 255) / 256, 256, 0, stream>>>(
        x, Wl1, Wr1, Wl2, Wr2, Wskip, bias1, bn_w, bn_b, bn_rm, bn_rv, ei, E, ET,
        xbf, wcat1, wcat2, deg, rpos, bnS, bnT, n4x);
  }

  // --- CSR: even-padded scan + atomic-free scatter (4 edges/thread) ---
  scan_deg<<<1, 1024, 0, stream>>>(deg, indptr, N);
  {
    int ST = (E + 3) / 4;
    scatter_edges<<<(ST + 255) / 256, 256, 0, stream>>>(ei, E, ST, indptr, rpos, csr);
  }

  // --- layer 1: [xl|xr|xres] = x @ [Wl1|Wr1|Wskip]^T ---
  {
    int mtiles = (N + 31) >> 5;
    int waves = mtiles * 5;
    gemm_bf16_mfma<true><<<(waves + 3) / 4, 256, 0, stream>>>(
        xbf, wcat1, bl1, br1, (unsigned short*)xlr, xres, N, 5);
  }

  // --- layer 1 aggregation -> packed bf16 h ---
  {
    int blocks = 2048, nwaves = blocks * 4;
    gat_agg<1><<<blocks, 256, 0, stream>>>(xlr, indptr, deg, csr, att1,
                                           bnS, bnT, nullptr, nullptr, (void*)hbf, N, nwaves);
  }

  // --- layer 2: [xl|xr] = h @ [Wl2|Wr2]^T ---
  {
    int mtiles = (N + 31) >> 5;
    int waves = mtiles * 4;
    gemm_bf16_mfma<false><<<(waves + 3) / 4, 256, 0, stream>>>(
        hbf, wcat2, bl2, br2, (unsigned short*)xlr, nullptr, N, 4);
  }

  // --- layer 2 aggregation -> out ---
  {
    int blocks = 2048, nwaves = blocks * 4;
    gat_agg<2><<<blocks, 256, 0, stream>>>(xlr, indptr, deg, csr, att2,
                                           xres, bias2, ln_w, ln_b, d_out, N, nwaves);
  }
}